// Round 1
// baseline (250.025 us; speedup 1.0000x reference)
//
#include <hip/hip_runtime.h>

typedef __attribute__((ext_vector_type(8))) short bf16x8;
typedef __attribute__((ext_vector_type(4))) float f32x4;

#define DEV static __device__ __forceinline__

DEV unsigned short f2bf(float f){
  union { float f; unsigned u; } v; v.f = f;
  unsigned r = v.u + 0x7fffu + ((v.u >> 16) & 1u);
  return (unsigned short)(r >> 16);
}
DEV float bf2f(unsigned short u){
  union { unsigned u; float f; } v; v.u = ((unsigned)u) << 16;
  return v.f;
}
DEV unsigned long long pk4(float a, float b, float c, float d){
  unsigned lo = (unsigned)f2bf(a) | ((unsigned)f2bf(b) << 16);
  unsigned hi = (unsigned)f2bf(c) | ((unsigned)f2bf(d) << 16);
  return ((unsigned long long)hi << 32) | lo;
}

// ---------------- transpose+convert: src [bat][R][C] f32 -> dst [bat][C][R] bf16
__global__ void k_tcvt(const float* __restrict__ src, unsigned short* __restrict__ dst,
                       int R, int C){
  __shared__ float tile[32][33];
  int bat = blockIdx.z;
  size_t boff = (size_t)bat * R * C;
  int c0 = blockIdx.x * 32, r0 = blockIdx.y * 32;
  int tx = threadIdx.x, ty = threadIdx.y;
  for (int i = 0; i < 4; i++)
    tile[ty + i*8][tx] = src[boff + (size_t)(r0 + ty + i*8) * C + c0 + tx];
  __syncthreads();
  for (int i = 0; i < 4; i++)
    dst[boff + (size_t)(c0 + ty + i*8) * R + r0 + tx] = f2bf(tile[tx][ty + i*8]);
}

// ---------------- plain convert f32 -> bf16 (vector4)
__global__ void k_cvt(const float* __restrict__ src, unsigned short* __restrict__ dst, int n4){
  int i = blockIdx.x * blockDim.x + threadIdx.x;
  if (i >= n4) return;
  f32x4 v = *(const f32x4*)(src + (size_t)i * 4);
  *(unsigned long long*)(dst + (size_t)i * 4) = pk4(v[0], v[1], v[2], v[3]);
}

// ---------------- router: logits -> softmax -> top2 -> normalized routing [4096][8]
__global__ __launch_bounds__(256) void k_router(const float* __restrict__ x,
                                                const float* __restrict__ Wr,
                                                const float* __restrict__ br,
                                                const float* __restrict__ bias0,
                                                float* __restrict__ routing){
  __shared__ float lg[32][8];
  __shared__ float rt[32][8];
  int t = threadIdx.x;
  int row = t >> 3, mm = t & 7;
  int n = blockIdx.x * 32 + row;                 // token 0..4095
  const float* xr = x + (size_t)n * 256;
  float acc = 0.f;
  for (int d = 0; d < 256; d++) acc += xr[d] * Wr[d * 8 + mm];
  acc += br[mm];
  lg[row][mm] = acc;
  __syncthreads();
  if (t < 32){
    int r = t; int n2 = blockIdx.x * 32 + r; int b = n2 >> 11;
    float mx = -1e30f;
    for (int i = 0; i < 8; i++) mx = fmaxf(mx, lg[r][i]);
    float s[8]; float sum = 0.f;
    for (int i = 0; i < 8; i++){ s[i] = __expf(lg[r][i] - mx); sum += s[i]; }
    for (int i = 0; i < 8; i++) s[i] /= sum;
    float bb[8];
    for (int i = 0; i < 8; i++) bb[i] = s[i] + bias0[b * 8 + i];
    int i1 = 0;
    for (int i = 1; i < 8; i++) if (bb[i] > bb[i1]) i1 = i;
    int i2 = -1;
    for (int i = 0; i < 8; i++){ if (i == i1) continue; if (i2 < 0 || bb[i] > bb[i2]) i2 = i; }
    float wsum = s[i1] + s[i2];
    for (int i = 0; i < 8; i++)
      rt[r][i] = (i == i1) ? s[i1] / wsum : ((i == i2) ? s[i2] / wsum : 0.f);
  }
  __syncthreads();
  routing[(size_t)n * 8 + mm] = rt[row][mm];
}

// ---------------- per-(b,m) token list compaction (deterministic, ordered by s)
__global__ __launch_bounds__(256) void k_lists(const float* __restrict__ routing,
                                               int* __restrict__ lists,
                                               int* __restrict__ counts){
  __shared__ int wsum[4];
  __shared__ int basec;
  int bm = blockIdx.x; int b = bm >> 3, mm = bm & 7;
  int t = threadIdx.x; int lane = t & 63, w = t >> 6;
  if (t == 0) basec = 0;
  __syncthreads();
  int* lst = lists + (size_t)bm * 2048;
  for (int ch = 0; ch < 8; ch++){
    int s = ch * 256 + t;
    int n = b * 2048 + s;
    bool f = routing[(size_t)n * 8 + mm] > 0.f;
    unsigned long long bal = __ballot(f);
    int pfx = __popcll(bal & ((1ull << lane) - 1ull));
    int tot = __popcll(bal);
    if (lane == 0) wsum[w] = tot;
    __syncthreads();
    int off = basec;
    for (int i = 0; i < w; i++) off += wsum[i];
    if (f) lst[off + pfx] = n;
    __syncthreads();
    if (t == 0) basec += wsum[0] + wsum[1] + wsum[2] + wsum[3];
    __syncthreads();
  }
  if (t == 0) counts[bm] = basec;
}

// ---------------- Q projection: Q[token][hd] = x @ Wq + bq (bf16 out)
__global__ __launch_bounds__(256) void k_qproj(const unsigned short* __restrict__ WqT,
                                               const unsigned short* __restrict__ xb,
                                               const float* __restrict__ bq,
                                               unsigned short* __restrict__ Q){
  int bid = blockIdx.x;                 // 2048 = 32 (hd blocks) * 64 (token blocks)
  int hdb = (bid & 31) * 64;
  int tkb = (bid >> 5) * 64;
  int t = threadIdx.x; int lane = t & 63, w = t >> 6;
  int li = lane & 15, lgp = lane >> 4;
  int tok0 = tkb + w * 16;
  f32x4 acc[4];
  for (int i = 0; i < 4; i++) acc[i] = (f32x4){0.f,0.f,0.f,0.f};
  const unsigned short* bptr = xb + (size_t)(tok0 + li) * 256 + lgp * 8;
  for (int kk = 0; kk < 8; kk++){
    bf16x8 bfr = *(const bf16x8*)(bptr + kk * 32);
    for (int ai = 0; ai < 4; ai++){
      bf16x8 afr = *(const bf16x8*)(WqT + (size_t)(hdb + ai*16 + li) * 256 + kk*32 + lgp*8);
      acc[ai] = __builtin_amdgcn_mfma_f32_16x16x32_bf16(afr, bfr, acc[ai], 0, 0, 0);
    }
  }
  int token = tok0 + li;
  for (int ai = 0; ai < 4; ai++){
    int hd0 = hdb + ai * 16 + lgp * 4;
    *(unsigned long long*)(Q + (size_t)token * 2048 + hd0) =
      pk4(acc[ai][0] + bq[hd0], acc[ai][1] + bq[hd0+1],
          acc[ai][2] + bq[hd0+2], acc[ai][3] + bq[hd0+3]);
  }
}

// ---------------- fused gather + K/V proj + weighted outer-product accumulation
__global__ __launch_bounds__(1024) void k_mem(const unsigned short* __restrict__ xb,
                                              const unsigned short* __restrict__ WkT,
                                              const unsigned short* __restrict__ WvT,
                                              const float* __restrict__ bk,
                                              const float* __restrict__ bv,
                                              const float* __restrict__ routing,
                                              const int* __restrict__ lists,
                                              const int* __restrict__ counts,
                                              unsigned short* __restrict__ partials){
  __shared__ unsigned short xls[32][264];   // [token][d], +8 pad
  __shared__ unsigned short kt[256][40];    // [kd][token], +8 pad (16B-aligned rows)
  __shared__ unsigned short vt[256][40];    // [vd][token]
  __shared__ float r_l[32];

  int bid = blockIdx.x;                     // 256 = b(2) m(8) h(8) c(2)
  int c  = bid & 1;
  int h  = (bid >> 1) & 7;
  int m  = (bid >> 4) & 7;
  int b  = bid >> 7;

  int t = threadIdx.x;
  int lane = t & 63, w = t >> 6;
  int li = lane & 15, lgp = lane >> 4;

  int cnt = counts[b * 8 + m];
  int ntiles = (cnt + 31) >> 5;
  const int* lst = lists + (size_t)(b * 8 + m) * 2048;

  int r4 = w >> 2, c4 = w & 3;              // wave grid 4x4 over (kd, vd)

  f32x4 acc[4][4];
  for (int i = 0; i < 4; i++) for (int j = 0; j < 4; j++) acc[i][j] = (f32x4){0.f,0.f,0.f,0.f};

  const unsigned short* wkp = WkT + ((size_t)m*2048 + h*256 + w*16 + li) * 256 + lgp*8;
  const unsigned short* wvp = WvT + ((size_t)m*2048 + h*256 + w*16 + li) * 256 + lgp*8;
  float bkv = bk[m*2048 + h*256 + w*16 + li];
  float bvv = bv[m*2048 + h*256 + w*16 + li];

  int srow = t >> 5, sch = t & 31;

  for (int tt = c; tt < ntiles; tt += 2){
    int base = tt * 32;
    {   // stage gathered x rows + routing weights
      int p = base + srow;
      int n = (p < cnt) ? lst[p] : 0;
      *(bf16x8*)(&xls[srow][sch * 8]) = *(const bf16x8*)(xb + (size_t)n * 256 + sch * 8);
      if (t < 32){
        int pp2 = base + t;
        r_l[t] = (pp2 < cnt) ? routing[(size_t)lst[pp2] * 8 + m] : 0.f;
      }
    }
    __syncthreads();
    // K/V projection: wave w owns kd/vd columns [16w, 16w+16)
    f32x4 ck0 = (f32x4){0,0,0,0}, ck1 = (f32x4){0,0,0,0};
    f32x4 cv0 = (f32x4){0,0,0,0}, cv1 = (f32x4){0,0,0,0};
    for (int kk = 0; kk < 8; kk++){
      bf16x8 bkf = *(const bf16x8*)(wkp + kk * 32);
      bf16x8 bvf = *(const bf16x8*)(wvp + kk * 32);
      bf16x8 a0 = *(const bf16x8*)(&xls[li][kk*32 + lgp*8]);
      bf16x8 a1 = *(const bf16x8*)(&xls[16 + li][kk*32 + lgp*8]);
      ck0 = __builtin_amdgcn_mfma_f32_16x16x32_bf16(a0, bkf, ck0, 0, 0, 0);
      cv0 = __builtin_amdgcn_mfma_f32_16x16x32_bf16(a0, bvf, cv0, 0, 0, 0);
      ck1 = __builtin_amdgcn_mfma_f32_16x16x32_bf16(a1, bkf, ck1, 0, 0, 0);
      cv1 = __builtin_amdgcn_mfma_f32_16x16x32_bf16(a1, bvf, cv1, 0, 0, 0);
    }
    {   // write K' (=r*(k+bk)) and V transposed [dim][token] to LDS
      int kd = w * 16 + li;
      int tl0 = lgp * 4;
      *(unsigned long long*)(&kt[kd][tl0]) =
        pk4((ck0[0]+bkv)*r_l[tl0], (ck0[1]+bkv)*r_l[tl0+1],
            (ck0[2]+bkv)*r_l[tl0+2], (ck0[3]+bkv)*r_l[tl0+3]);
      *(unsigned long long*)(&vt[kd][tl0]) = pk4(cv0[0]+bvv, cv0[1]+bvv, cv0[2]+bvv, cv0[3]+bvv);
      int tl1 = 16 + lgp * 4;
      *(unsigned long long*)(&kt[kd][tl1]) =
        pk4((ck1[0]+bkv)*r_l[tl1], (ck1[1]+bkv)*r_l[tl1+1],
            (ck1[2]+bkv)*r_l[tl1+2], (ck1[3]+bkv)*r_l[tl1+3]);
      *(unsigned long long*)(&vt[kd][tl1]) = pk4(cv1[0]+bvv, cv1[1]+bvv, cv1[2]+bvv, cv1[3]+bvv);
    }
    __syncthreads();
    {   // outer-product accumulate: mem[kd][vd] += K'_tile^T(32tok) x V_tile
      bf16x8 av[4];
      for (int j = 0; j < 4; j++)
        av[j] = *(const bf16x8*)(&vt[c4*64 + j*16 + li][lgp*8]);
      for (int i = 0; i < 4; i++){
        bf16x8 ak = *(const bf16x8*)(&kt[r4*64 + i*16 + li][lgp*8]);
        for (int j = 0; j < 4; j++)
          acc[i][j] = __builtin_amdgcn_mfma_f32_16x16x32_bf16(ak, av[j], acc[i][j], 0, 0, 0);
      }
    }
  }
  // store partial as memT layout [vd][kd] (bf16)
  unsigned short* pp = partials + (size_t)bid * 65536;
  for (int j = 0; j < 4; j++){
    int vd = c4 * 64 + j * 16 + li;
    for (int i = 0; i < 4; i++){
      int kd0 = r4 * 64 + i * 16 + lgp * 4;
      *(unsigned long long*)(pp + (size_t)vd * 256 + kd0) =
        pk4(acc[i][j][0], acc[i][j][1], acc[i][j][2], acc[i][j][3]);
    }
  }
}

// ---------------- reduce 16 partials -> memT[b][h][vd][kd] bf16
__global__ __launch_bounds__(256) void k_reduce(const unsigned short* __restrict__ partials,
                                                unsigned short* __restrict__ memT){
  int idx = blockIdx.x * 256 + threadIdx.x;    // 262144 threads, 4 elems each
  int bh = idx >> 14;
  int e4 = idx & 16383;
  int b = bh >> 3, h = bh & 7;
  float s0 = 0, s1 = 0, s2 = 0, s3 = 0;
  for (int mc = 0; mc < 16; mc++){
    int m = mc >> 1, cc = mc & 1;
    const unsigned short* p = partials + ((size_t)(b*128 + m*16 + h*2 + cc)) * 65536 + (size_t)e4 * 4;
    unsigned long long v = *(const unsigned long long*)p;
    s0 += bf2f((unsigned short)(v));
    s1 += bf2f((unsigned short)(v >> 16));
    s2 += bf2f((unsigned short)(v >> 32));
    s3 += bf2f((unsigned short)(v >> 48));
  }
  *(unsigned long long*)(memT + (size_t)bh * 65536 + (size_t)e4 * 4) = pk4(s0, s1, s2, s3);
}

// ---------------- readout: O[token][h*256+vd] = sum_kd q[kd] * mem[kd][vd]
__global__ __launch_bounds__(256) void k_readout(const unsigned short* __restrict__ memT,
                                                 const unsigned short* __restrict__ Q,
                                                 unsigned short* __restrict__ O){
  int bid = blockIdx.x;                 // 512 = b(2) h(8) tokblk(32)
  int tb = bid & 31, h = (bid >> 5) & 7, b = bid >> 8;
  int t = threadIdx.x; int lane = t & 63, w = t >> 6;
  int li = lane & 15, lgp = lane >> 4;
  const unsigned short* mT = memT + (size_t)(b * 8 + h) * 65536;
  int vd0 = w * 64;
  int tokg = b * 2048 + tb * 64;
  f32x4 acc[4][4];
  for (int i = 0; i < 4; i++) for (int j = 0; j < 4; j++) acc[i][j] = (f32x4){0.f,0.f,0.f,0.f};
  for (int kk = 0; kk < 8; kk++){
    bf16x8 a[4], bb[4];
    for (int i = 0; i < 4; i++)
      a[i] = *(const bf16x8*)(mT + (size_t)(vd0 + i*16 + li) * 256 + kk*32 + lgp*8);
    for (int j = 0; j < 4; j++)
      bb[j] = *(const bf16x8*)(Q + (size_t)(tokg + j*16 + li) * 2048 + h*256 + kk*32 + lgp*8);
    for (int i = 0; i < 4; i++)
      for (int j = 0; j < 4; j++)
        acc[i][j] = __builtin_amdgcn_mfma_f32_16x16x32_bf16(a[i], bb[j], acc[i][j], 0, 0, 0);
  }
  for (int j = 0; j < 4; j++){
    int token = tokg + j * 16 + li;
    for (int i = 0; i < 4; i++){
      int vd = vd0 + i * 16 + lgp * 4;
      *(unsigned long long*)(O + (size_t)token * 2048 + h * 256 + vd) =
        pk4(acc[i][j][0], acc[i][j][1], acc[i][j][2], acc[i][j][3]);
    }
  }
}

// ---------------- final: out[token][dout] = O @ Wo + bo (f32 out)
__global__ __launch_bounds__(256) void k_final(const unsigned short* __restrict__ WoT,
                                               const unsigned short* __restrict__ O,
                                               const float* __restrict__ bo,
                                               float* __restrict__ out){
  int bid = blockIdx.x;                 // 256 = 4 (dout blocks) * 64 (token blocks)
  int db = (bid & 3) * 64, tkb = (bid >> 2) * 64;
  int t = threadIdx.x; int lane = t & 63, w = t >> 6;
  int li = lane & 15, lgp = lane >> 4;
  int tok0 = tkb + w * 16;
  f32x4 acc[4];
  for (int i = 0; i < 4; i++) acc[i] = (f32x4){0.f,0.f,0.f,0.f};
  for (int kk = 0; kk < 64; kk++){
    bf16x8 bfr = *(const bf16x8*)(O + (size_t)(tok0 + li) * 2048 + kk*32 + lgp*8);
    for (int ai = 0; ai < 4; ai++){
      bf16x8 afr = *(const bf16x8*)(WoT + (size_t)(db + ai*16 + li) * 2048 + kk*32 + lgp*8);
      acc[ai] = __builtin_amdgcn_mfma_f32_16x16x32_bf16(afr, bfr, acc[ai], 0, 0, 0);
    }
  }
  int token = tok0 + li;
  for (int ai = 0; ai < 4; ai++){
    int d0 = db + ai * 16 + lgp * 4;
    f32x4 v = acc[ai];
    v[0] += bo[d0]; v[1] += bo[d0+1]; v[2] += bo[d0+2]; v[3] += bo[d0+3];
    *(f32x4*)(out + (size_t)token * 256 + d0) = v;
  }
}

extern "C" void kernel_launch(void* const* d_in, const int* in_sizes, int n_in,
                              void* d_out, int out_size, void* d_ws, size_t ws_size,
                              hipStream_t stream) {
  const float* x     = (const float*)d_in[0];
  const float* Wq    = (const float*)d_in[1];
  const float* bq    = (const float*)d_in[2];
  const float* Wr    = (const float*)d_in[3];
  const float* br    = (const float*)d_in[4];
  const float* Wk    = (const float*)d_in[5];
  const float* bk    = (const float*)d_in[6];
  const float* Wv    = (const float*)d_in[7];
  const float* bv    = (const float*)d_in[8];
  const float* Wo    = (const float*)d_in[9];
  const float* bo    = (const float*)d_in[10];
  const float* bias0 = (const float*)d_in[11];
  float* out = (float*)d_out;

  char* ws = (char*)d_ws;
  size_t off = 0;
  auto alloc = [&](size_t bytes) -> char* {
    char* p = ws + off;
    off = (off + bytes + 255) & ~(size_t)255;
    return p;
  };
  unsigned short* xb   = (unsigned short*)alloc((size_t)4096 * 256 * 2);      // 2 MB
  unsigned short* WqT  = (unsigned short*)alloc((size_t)2048 * 256 * 2);      // 1 MB
  unsigned short* WkT  = (unsigned short*)alloc((size_t)8 * 2048 * 256 * 2);  // 8 MB
  unsigned short* WvT  = (unsigned short*)alloc((size_t)8 * 2048 * 256 * 2);  // 8 MB
  unsigned short* WoT  = (unsigned short*)alloc((size_t)256 * 2048 * 2);      // 1 MB
  unsigned short* Q    = (unsigned short*)alloc((size_t)4096 * 2048 * 2);     // 16 MB
  unsigned short* O    = (unsigned short*)alloc((size_t)4096 * 2048 * 2);     // 16 MB
  float*          rout = (float*)alloc((size_t)4096 * 8 * 4);                 // 128 KB
  int*            lst  = (int*)alloc((size_t)16 * 2048 * 4);                  // 128 KB
  int*            cnts = (int*)alloc((size_t)16 * 4);
  unsigned short* part = (unsigned short*)alloc((size_t)256 * 65536 * 2);     // 32 MB
  unsigned short* memT = (unsigned short*)alloc((size_t)16 * 65536 * 2);      // 2 MB
  (void)ws_size; (void)in_sizes; (void)n_in; (void)out_size;

  dim3 tb(32, 8, 1);
  // weights -> transposed bf16
  k_tcvt<<<dim3(64, 8, 1), tb, 0, stream>>>(Wq, WqT, 256, 2048);
  k_tcvt<<<dim3(64, 8, 8), tb, 0, stream>>>(Wk, WkT, 256, 2048);
  k_tcvt<<<dim3(64, 8, 8), tb, 0, stream>>>(Wv, WvT, 256, 2048);
  k_tcvt<<<dim3(8, 64, 1), tb, 0, stream>>>(Wo, WoT, 2048, 256);
  // x -> bf16
  k_cvt<<<1024, 256, 0, stream>>>(x, xb, 262144);
  // router + token lists
  k_router<<<128, 256, 0, stream>>>(x, Wr, br, bias0, rout);
  k_lists<<<16, 256, 0, stream>>>(rout, lst, cnts);
  // Q projection
  k_qproj<<<2048, 256, 0, stream>>>(WqT, xb, bq, Q);
  // memory accumulation (sparse, gathered)
  k_mem<<<256, 1024, 0, stream>>>(xb, WkT, WvT, bk, bv, rout, lst, cnts, part);
  k_reduce<<<1024, 256, 0, stream>>>(part, memT);
  // readout + output projection
  k_readout<<<512, 256, 0, stream>>>(memT, Q, O);
  k_final<<<256, 256, 0, stream>>>(WoT, O, bo, out);
}